// Round 1
// baseline (75.359 us; speedup 1.0000x reference)
//
#include <hip/hip_runtime.h>

// Batched CA_event RHS: out[i] = (dx, dy, -dx, -dy) per system.
// Constants from the reference:
//   A1=A2=1, B1=B2=0.2, K_DEG=1.1, HILL_N=2, S_HALF=0.5 -> sn=0.25, SCALE=10

__device__ __forceinline__ float4 ca_one(float x, float y, float ex, float ey,
                                         float wa0, float wa1,
                                         float t0, float t1) {
    const float sn = 0.25f;
    float xs = x * 0.1f;
    float ys = y * 0.1f;
    float xn = xs * xs;
    float yn = ys * ys;
    float invx = 1.0f / (sn + xn);   // serves hx and ry
    float invy = 1.0f / (sn + yn);   // serves hy and rx
    float hx = xn * invx;
    float hy = yn * invy;
    float rx = sn * invy;
    float ry = sn * invx;
    float u = wa0 * ((x + ex) - t0) + wa1 * ((y + ey) - t1);
    float dx = 10.0f * (hx + 0.2f * rx - 1.1f * xs + u * hx);
    float dy = 10.0f * (hy + 0.2f * ry - 1.1f * ys);
    return make_float4(dx, dy, -dx, -dy);
}

__global__ __launch_bounds__(256) void ca_event_kernel(
    const float* __restrict__ x, const float* __restrict__ y,
    const float* __restrict__ ex, const float* __restrict__ ey,
    const float* __restrict__ wa, const float* __restrict__ target,
    float* __restrict__ out, int n4) {
    int t = blockIdx.x * blockDim.x + threadIdx.x;
    if (t >= n4) return;

    const float t0 = target[0];
    const float t1 = target[1];

    float4 xv  = reinterpret_cast<const float4*>(x)[t];
    float4 yv  = reinterpret_cast<const float4*>(y)[t];
    float4 exv = reinterpret_cast<const float4*>(ex)[t];
    float4 eyv = reinterpret_cast<const float4*>(ey)[t];
    float4 w01 = reinterpret_cast<const float4*>(wa)[2 * t + 0]; // Wa[4t+0], Wa[4t+1]
    float4 w23 = reinterpret_cast<const float4*>(wa)[2 * t + 1]; // Wa[4t+2], Wa[4t+3]

    float4 o0 = ca_one(xv.x, yv.x, exv.x, eyv.x, w01.x, w01.y, t0, t1);
    float4 o1 = ca_one(xv.y, yv.y, exv.y, eyv.y, w01.z, w01.w, t0, t1);
    float4 o2 = ca_one(xv.z, yv.z, exv.z, eyv.z, w23.x, w23.y, t0, t1);
    float4 o3 = ca_one(xv.w, yv.w, exv.w, eyv.w, w23.z, w23.w, t0, t1);

    float4* o = reinterpret_cast<float4*>(out) + 4 * t;
    o[0] = o0;
    o[1] = o1;
    o[2] = o2;
    o[3] = o3;
}

extern "C" void kernel_launch(void* const* d_in, const int* in_sizes, int n_in,
                              void* d_out, int out_size, void* d_ws, size_t ws_size,
                              hipStream_t stream) {
    const float* x      = (const float*)d_in[0];
    const float* y      = (const float*)d_in[1];
    const float* ex     = (const float*)d_in[2];
    const float* ey     = (const float*)d_in[3];
    const float* wa     = (const float*)d_in[4];
    const float* target = (const float*)d_in[5];
    float* out = (float*)d_out;

    int n = in_sizes[0];          // B = 8388608 (divisible by 4)
    int n4 = n / 4;
    int block = 256;
    int grid = (n4 + block - 1) / block;
    ca_event_kernel<<<grid, block, 0, stream>>>(x, y, ex, ey, wa, target, out, n4);
}

// Round 2
// 64.065 us; speedup vs baseline: 1.1763x; 1.1763x over previous
//
#include <hip/hip_runtime.h>

// Batched CA_event RHS: out[s] = (dx, dy, -dx, -dy) per system s.
// Constants: A1=A2=1, B1=B2=0.2, K_DEG=1.1, HILL_N=2, S_HALF=0.5 -> sn=0.25, SCALE=10
//
// Layout choice: 1 system per thread so EVERY stream is per-instruction
// unit-density coalesced:
//   x/y/ex/ey: 4 B/lane stride-4; W_a: float2 8 B/lane stride-8;
//   out: one float4 16 B/lane stride-16.
// (4 systems/thread made wa loads 50%-density and out stores 25%-density
//  per instruction -> 3.1 TB/s ceiling observed.)

__global__ __launch_bounds__(256) void ca_event_kernel(
    const float* __restrict__ x, const float* __restrict__ y,
    const float* __restrict__ ex, const float* __restrict__ ey,
    const float* __restrict__ wa, const float* __restrict__ target,
    float* __restrict__ out, int n) {
    int s = blockIdx.x * blockDim.x + threadIdx.x;
    if (s >= n) return;

    const float t0 = target[0];
    const float t1 = target[1];

    float xv = x[s];
    float yv = y[s];
    float exv = ex[s];
    float eyv = ey[s];
    float2 w = reinterpret_cast<const float2*>(wa)[s];

    const float sn = 0.25f;
    float xs = xv * 0.1f;
    float ys = yv * 0.1f;
    float xn = xs * xs;
    float yn = ys * ys;
    float invx = 1.0f / (sn + xn);   // serves hx and ry
    float invy = 1.0f / (sn + yn);   // serves hy and rx
    float hx = xn * invx;
    float hy = yn * invy;
    float rx = sn * invy;
    float ry = sn * invx;
    float u = w.x * ((xv + exv) - t0) + w.y * ((yv + eyv) - t1);
    float dx = 10.0f * (hx + 0.2f * rx - 1.1f * xs + u * hx);
    float dy = 10.0f * (hy + 0.2f * ry - 1.1f * ys);

    reinterpret_cast<float4*>(out)[s] = make_float4(dx, dy, -dx, -dy);
}

extern "C" void kernel_launch(void* const* d_in, const int* in_sizes, int n_in,
                              void* d_out, int out_size, void* d_ws, size_t ws_size,
                              hipStream_t stream) {
    const float* x      = (const float*)d_in[0];
    const float* y      = (const float*)d_in[1];
    const float* ex     = (const float*)d_in[2];
    const float* ey     = (const float*)d_in[3];
    const float* wa     = (const float*)d_in[4];
    const float* target = (const float*)d_in[5];
    float* out = (float*)d_out;

    int n = in_sizes[0];          // B = 8388608
    int block = 256;
    int grid = (n + block - 1) / block;   // 32768 blocks
    ca_event_kernel<<<grid, block, 0, stream>>>(x, y, ex, ey, wa, target, out, n);
}

// Round 4
// 52.176 us; speedup vs baseline: 1.4443x; 1.2279x over previous
//
#include <hip/hip_runtime.h>

// Batched CA_event RHS: out[s] = (dx, dy, -dx, -dy) per system s.
// Constants: A1=A2=1, B1=B2=0.2, K_DEG=1.1, HILL_N=2, S_HALF=0.5 -> sn=0.25, SCALE=10
//
// 1 system/thread: every stream per-instruction unit-density coalesced.
// Output stores are NONTEMPORAL: the 134 MB write stream otherwise evicts
// the 201 MB input set from the 256 MB Infinity Cache (observed: FETCH_SIZE
// 98 MB/replay = re-fetch of evicted inputs). nt stores keep inputs L3-resident
// across graph replays -> HBM traffic ~= write stream only.
//
// NOTE: __builtin_nontemporal_store requires a clang native vector type,
// not HIP_vector_type (float4) — use ext_vector_type(4).

typedef float floatx4 __attribute__((ext_vector_type(4)));

__global__ __launch_bounds__(256) void ca_event_kernel(
    const float* __restrict__ x, const float* __restrict__ y,
    const float* __restrict__ ex, const float* __restrict__ ey,
    const float* __restrict__ wa, const float* __restrict__ target,
    float* __restrict__ out, int n) {
    int s = blockIdx.x * blockDim.x + threadIdx.x;
    if (s >= n) return;

    const float t0 = target[0];
    const float t1 = target[1];

    float xv = x[s];
    float yv = y[s];
    float exv = ex[s];
    float eyv = ey[s];
    float2 w = reinterpret_cast<const float2*>(wa)[s];

    const float sn = 0.25f;
    float xs = xv * 0.1f;
    float ys = yv * 0.1f;
    float xn = xs * xs;
    float yn = ys * ys;
    float invx = 1.0f / (sn + xn);   // serves hx and ry
    float invy = 1.0f / (sn + yn);   // serves hy and rx
    float hx = xn * invx;
    float hy = yn * invy;
    float rx = sn * invy;
    float ry = sn * invx;
    float u = w.x * ((xv + exv) - t0) + w.y * ((yv + eyv) - t1);
    float dx = 10.0f * (hx + 0.2f * rx - 1.1f * xs + u * hx);
    float dy = 10.0f * (hy + 0.2f * ry - 1.1f * ys);

    floatx4 o = {dx, dy, -dx, -dy};
    __builtin_nontemporal_store(o, reinterpret_cast<floatx4*>(out) + s);
}

extern "C" void kernel_launch(void* const* d_in, const int* in_sizes, int n_in,
                              void* d_out, int out_size, void* d_ws, size_t ws_size,
                              hipStream_t stream) {
    const float* x      = (const float*)d_in[0];
    const float* y      = (const float*)d_in[1];
    const float* ex     = (const float*)d_in[2];
    const float* ey     = (const float*)d_in[3];
    const float* wa     = (const float*)d_in[4];
    const float* target = (const float*)d_in[5];
    float* out = (float*)d_out;

    int n = in_sizes[0];          // B = 8388608
    int block = 256;
    int grid = (n + block - 1) / block;   // 32768 blocks
    ca_event_kernel<<<grid, block, 0, stream>>>(x, y, ex, ey, wa, target, out, n);
}